// Round 15
// baseline (225.393 us; speedup 1.0000x reference)
//
#include <hip/hip_runtime.h>

#define CI 32
#define CO 32
#define PD 64
#define QDIM 1024
#define M_TOTAL (32*4096)
#define TILE_M 256                 // per WG: 2 waves x 4 row-blocks x 32 rows
#define NBLK (M_TOTAL/TILE_M)      // 512 WGs
#define WG_THREADS 128
#define XLS 257

typedef float  f32x4  __attribute__((ext_vector_type(4)));
typedef float  f32x16 __attribute__((ext_vector_type(16)));
typedef __bf16 bf16x4 __attribute__((ext_vector_type(4)));
typedef __bf16 bf16x8 __attribute__((ext_vector_type(8)));

// ---- one-time: Wk [64][1024] f32 -> wsF, MFMA-A-fragment-linear layout ----
// wsF idx = (q>>5)*2048 + (k>>3)*256 + (q&31)*8 + (k&7); per i, frag f, lane
// (l31,hi) reads contiguous: wsF + i*2048 + (2f+hi)*256 + l31*8
__global__ __launch_bounds__(256)
void wk_pack_kernel(const float* __restrict__ Wk, __bf16* __restrict__ wsF)
{
    __shared__ float tile[64][33];
    const int q0 = blockIdx.x * 32;
    const int t  = threadIdx.x;
#pragma unroll
    for (int s = 0; s < 2; ++s) {
        const int idx = t + s * 256;
        const int k = idx >> 3, ch = idx & 7;
        f32x4 v = *(const f32x4*)(Wk + (size_t)k * QDIM + q0 + ch * 4);
        tile[k][ch*4+0] = v[0]; tile[k][ch*4+1] = v[1];
        tile[k][ch*4+2] = v[2]; tile[k][ch*4+3] = v[3];
    }
    __syncthreads();
    const int qq = t >> 3;
    const int g  = t & 7;
    bf16x8 o;
#pragma unroll
    for (int j = 0; j < 8; ++j) o[j] = (__bf16)tile[g*8 + j][qq];
    *(bf16x8*)(wsF + (size_t)blockIdx.x * 2048 + g * 256 + qq * 8) = o;
}

// Shared prologue/loop body via macros so main and diagnostics stay identical.
#define PROLOGUE_STAGE_AND_BFRAG                                               \
    const int t   = threadIdx.x;                                               \
    const int l   = t & 63;                                                    \
    const int w   = t >> 6;        /* wave 0/1 -> rows w*128.. */              \
    const int l31 = l & 31;                                                    \
    const int hi  = l >> 5;                                                    \
    const int tile0 = blockIdx.x * TILE_M;                                     \
    {   /* P[256][64] -> bf16 swizzled LDS */                                  \
        const float* Pb = Pg + (size_t)tile0 * PD;                             \
        _Pragma("unroll")                                                      \
        for (int s = 0; s < 32; ++s) {                                         \
            const int id = t + 128 * s;                                        \
            const int r = id >> 4, ch = id & 15;                               \
            f32x4 v = *(const f32x4*)(Pb + (size_t)r * PD + ch * 4);           \
            bf16x4 bv;                                                         \
            _Pragma("unroll")                                                  \
            for (int j = 0; j < 4; ++j) bv[j] = (__bf16)v[j];                  \
            char* dst = (char*)Pl + r * 128                                    \
                      + ((((ch >> 1) ^ (r & 7)) << 4) | ((ch & 1) * 8));       \
            *(bf16x4*)dst = bv;                                                \
        }                                                                      \
        const float* Xb = Xg + (size_t)tile0 * CI;                             \
        _Pragma("unroll")                                                      \
        for (int s = 0; s < 16; ++s) {                                         \
            const int id = t + 128 * s;                                        \
            const int r = id >> 3, ch = id & 7;                                \
            f32x4 v = *(const f32x4*)(Xb + (size_t)r * CI + ch * 4);           \
            _Pragma("unroll")                                                  \
            for (int j = 0; j < 4; ++j) Xl[(ch * 4 + j) * XLS + r] = v[j];     \
        }                                                                      \
    }                                                                          \
    __syncthreads();                                                           \
    bf16x8 bf[4][4];   /* P^T fragments for 4 row-blocks: 64 VGPR */           \
    _Pragma("unroll")                                                          \
    for (int rb = 0; rb < 4; ++rb) {                                           \
        const int row = w * 128 + rb * 32 + l31;                               \
        _Pragma("unroll")                                                      \
        for (int kq = 0; kq < 4; ++kq) {                                       \
            const int g = ((kq * 2 + hi) ^ (l31 & 7)) << 4;                    \
            bf[rb][kq] = *(const bf16x8*)((const char*)Pl + row * 128 + g);    \
        }                                                                      \
    }

#define ALOAD(i, buf)                                                          \
    {   const __bf16* ap_ = abase + (size_t)(i) * 2048;                        \
        (buf)[0] = *(const bf16x8*)(ap_);                                      \
        (buf)[1] = *(const bf16x8*)(ap_ +  512);                               \
        (buf)[2] = *(const bf16x8*)(ap_ + 1024);                               \
        (buf)[3] = *(const bf16x8*)(ap_ + 1536);  }

#define STEP(a, i)                                                             \
    {   const int xb_ = (i) * XLS + w * 128 + l31;                             \
        const float x0_ = Xl[xb_], x1_ = Xl[xb_ + 32],                         \
                    x2_ = Xl[xb_ + 64], x3_ = Xl[xb_ + 96];                    \
        f32x16 c0 = {}, c1 = {}, c2 = {}, c3 = {};                             \
        _Pragma("unroll")                                                      \
        for (int kq = 0; kq < 4; ++kq) {   /* 4 independent chains */          \
            c0 = __builtin_amdgcn_mfma_f32_32x32x16_bf16((a)[kq], bf[0][kq], c0, 0, 0, 0); \
            c1 = __builtin_amdgcn_mfma_f32_32x32x16_bf16((a)[kq], bf[1][kq], c1, 0, 0, 0); \
            c2 = __builtin_amdgcn_mfma_f32_32x32x16_bf16((a)[kq], bf[2][kq], c2, 0, 0, 0); \
            c3 = __builtin_amdgcn_mfma_f32_32x32x16_bf16((a)[kq], bf[3][kq], c3, 0, 0, 0); \
        }                                                                      \
        _Pragma("unroll")                                                      \
        for (int r = 0; r < 16; ++r) {                                         \
            oa0[r] += fmaxf(c0[r], 0.0f) * x0_;                                \
            oa1[r] += fmaxf(c1[r], 0.0f) * x1_;                                \
            oa2[r] += fmaxf(c2[r], 0.0f) * x2_;                                \
            oa3[r] += fmaxf(c3[r], 0.0f) * x3_;  } }

// ---- MAIN: R=4 rows/wave (halves per-CU A-traffic vs R12's R=2) ----
__global__ __launch_bounds__(WG_THREADS, 2)
void cond_dense_kernel(const float* __restrict__ Xg, const float* __restrict__ Pg,
                       const __bf16* __restrict__ wsF, float* __restrict__ outg)
{
    __shared__ __bf16 Pl[TILE_M * PD];   // 32 KB
    __shared__ float  Xl[CI * XLS];      // 32.9 KB
    PROLOGUE_STAGE_AND_BFRAG
    f32x16 oa0 = {}, oa1 = {}, oa2 = {}, oa3 = {};
    const __bf16* abase = wsF + (size_t)hi * 256 + (size_t)l31 * 8;
    bf16x8 a0[4], a1[4];
    ALOAD(0, a0) ALOAD(1, a1)
    for (int ii = 0; ii < 16; ++ii) {
        STEP(a0, 2 * ii)
        if (ii < 15) ALOAD(2 * ii + 2, a0)
        STEP(a1, 2 * ii + 1)
        if (ii < 15) ALOAD(2 * ii + 3, a1)
    }
    // direct stores: full 128B lines completed within this wave
#pragma unroll
    for (int rb = 0; rb < 4; ++rb) {
        const f32x16& oo = rb == 0 ? oa0 : rb == 1 ? oa1 : rb == 2 ? oa2 : oa3;
        float* orow = outg + (size_t)(tile0 + w * 128 + rb * 32 + l31) * CO + 4 * hi;
#pragma unroll
        for (int rq = 0; rq < 4; ++rq) {
            f32x4 v;
#pragma unroll
            for (int j = 0; j < 4; ++j) v[j] = oo[4 * rq + j];
            *(f32x4*)(orow + 8 * rq) = v;
        }
    }
}

// ---- DIAG A: full structure, i-loop x4 reps, sink-store (d_ws) ----
__global__ __launch_bounds__(WG_THREADS, 2)
void cond_diag_full(const float* __restrict__ Xg, const float* __restrict__ Pg,
                    const __bf16* __restrict__ wsF, float* __restrict__ sink)
{
    __shared__ __bf16 Pl[TILE_M * PD];
    __shared__ float  Xl[CI * XLS];
    PROLOGUE_STAGE_AND_BFRAG
    f32x16 oa0 = {}, oa1 = {}, oa2 = {}, oa3 = {};
    const __bf16* abase = wsF + (size_t)hi * 256 + (size_t)l31 * 8;
    bf16x8 a0[4], a1[4];
#pragma unroll 1
    for (int rep = 0; rep < 4; ++rep) {
        ALOAD(0, a0) ALOAD(1, a1)
        for (int ii = 0; ii < 16; ++ii) {
            STEP(a0, 2 * ii)
            if (ii < 15) ALOAD(2 * ii + 2, a0)
            STEP(a1, 2 * ii + 1)
            if (ii < 15) ALOAD(2 * ii + 3, a1)
        }
    }
    float s = 0;
#pragma unroll
    for (int r = 0; r < 16; ++r) s += oa0[r] + oa1[r] + oa2[r] + oa3[r];
    sink[(size_t)blockIdx.x * WG_THREADS + t] = s;
}

// ---- DIAG B: identical but A loaded ONCE (zero A-traffic in loop) ----
__global__ __launch_bounds__(WG_THREADS, 2)
void cond_diag_noa(const float* __restrict__ Xg, const float* __restrict__ Pg,
                   const __bf16* __restrict__ wsF, float* __restrict__ sink)
{
    __shared__ __bf16 Pl[TILE_M * PD];
    __shared__ float  Xl[CI * XLS];
    PROLOGUE_STAGE_AND_BFRAG
    f32x16 oa0 = {}, oa1 = {}, oa2 = {}, oa3 = {};
    const __bf16* abase = wsF + (size_t)hi * 256 + (size_t)l31 * 8;
    bf16x8 a0[4], a1[4];
    ALOAD(0, a0) ALOAD(1, a1)
#pragma unroll 1
    for (int rep = 0; rep < 4; ++rep) {
        for (int ii = 0; ii < 16; ++ii) {    // reuse a0/a1: wrong data, live ops
            STEP(a0, 2 * ii)
            STEP(a1, 2 * ii + 1)
        }
    }
    float s = 0;
#pragma unroll
    for (int r = 0; r < 16; ++r) s += oa0[r] + oa1[r] + oa2[r] + oa3[r];
    sink[(size_t)blockIdx.x * WG_THREADS + t] = s;
}

extern "C" void kernel_launch(void* const* d_in, const int* in_sizes, int n_in,
                              void* d_out, int out_size, void* d_ws, size_t ws_size,
                              hipStream_t stream)
{
    const float* X  = (const float*)d_in[0];
    const float* P  = (const float*)d_in[1];
    const float* Wk = (const float*)d_in[2];
    float* out  = (float*)d_out;
    __bf16* wsF = (__bf16*)d_ws;                          // 128 KB at offset 0
    float* sink = (float*)((char*)d_ws + (16u << 20));    // diag sink at +16 MB

    wk_pack_kernel<<<dim3(QDIM / 32), dim3(256), 0, stream>>>(Wk, wsF);
    cond_dense_kernel<<<dim3(NBLK), dim3(WG_THREADS), 0, stream>>>(X, P, wsF, out);
    cond_diag_full<<<dim3(NBLK), dim3(WG_THREADS), 0, stream>>>(X, P, wsF, sink);
    cond_diag_noa<<<dim3(NBLK), dim3(WG_THREADS), 0, stream>>>(X, P, wsF, sink);
}

// Round 16
// 87.412 us; speedup vs baseline: 2.5785x; 2.5785x over previous
//
#include <hip/hip_runtime.h>

#define CI 32
#define CO 32
#define PD 64
#define QDIM 1024
#define M_TOTAL (32*4096)
#define TILE_M 128                 // per WG: waves = (rg in 0..1) x (ih in 0..1)
#define NBLK (M_TOTAL/TILE_M)      // 1024 WGs -> 4 per CU, 16 waves/CU = 4/SIMD
#define WG_THREADS 256
#define XLS 33                     // Xl[m][i]: reads (l31+i)%32 conflict-free
#define OLS 33                     // Ol[lane][r]: (l+r)%32, 2-way free

typedef float  f32x4  __attribute__((ext_vector_type(4)));
typedef float  f32x16 __attribute__((ext_vector_type(16)));
typedef __bf16 bf16x4 __attribute__((ext_vector_type(4)));
typedef __bf16 bf16x8 __attribute__((ext_vector_type(8)));

// ---- one-time: Wk [64][1024] f32 -> wsF, MFMA-A-fragment-linear layout ----
// wsF idx = (q>>5)*2048 + (k>>3)*256 + (q&31)*8 + (k&7); per i, frag f, lane
// (l31,hi) reads contiguous: wsF + i*2048 + (2f+hi)*256 + l31*8
__global__ __launch_bounds__(256)
void wk_pack_kernel(const float* __restrict__ Wk, __bf16* __restrict__ wsF)
{
    __shared__ float tile[64][33];
    const int q0 = blockIdx.x * 32;
    const int t  = threadIdx.x;
#pragma unroll
    for (int s = 0; s < 2; ++s) {
        const int idx = t + s * 256;
        const int k = idx >> 3, ch = idx & 7;
        f32x4 v = *(const f32x4*)(Wk + (size_t)k * QDIM + q0 + ch * 4);
        tile[k][ch*4+0] = v[0]; tile[k][ch*4+1] = v[1];
        tile[k][ch*4+2] = v[2]; tile[k][ch*4+3] = v[3];
    }
    __syncthreads();
    const int qq = t >> 3;
    const int g  = t & 7;
    bf16x8 o;
#pragma unroll
    for (int j = 0; j < 8; ++j) o[j] = (__bf16)tile[g*8 + j][qq];
    *(bf16x8*)(wsF + (size_t)blockIdx.x * 2048 + g * 256 + qq * 8) = o;
}

// i-SPLIT scheme: R15 ablation proved the STEP body (VALU relu+fma) is the
// wall and it was running at 1 wave/SIMD (issue stalls ~80% exposed). Here
// each wave does HALF the i-range for 64 rows -> 4096 waves = 4/SIMD at
// VGPR~115, totals (MFMA, VALU, A-traffic) unchanged. Partials combined via
// LDS: ih=1 writes, ih=0 adds + stores.
__global__ __launch_bounds__(WG_THREADS, 4)
void cond_dense_kernel(const float* __restrict__ Xg, const float* __restrict__ Pg,
                       const __bf16* __restrict__ wsF, float* __restrict__ outg)
{
    __shared__ union {
        __bf16 p[TILE_M * PD];       // 16384 B: P-tile (dead after bfrag)
        float  o[2 * 64 * OLS];      // 16896 B: partial-sum exchange
    } U;
    __shared__ float Xl[TILE_M * XLS];   // 16896 B: X row-major [m][i]

    const int t   = threadIdx.x;
    const int l   = t & 63;
    const int w   = t >> 6;
    const int rg  = w & 1;          // row-group: rows rg*64 .. rg*64+63
    const int ih  = w >> 1;         // i-half: i in ih*16 .. ih*16+15
    const int l31 = l & 31;
    const int hi  = l >> 5;
    const int tile0 = blockIdx.x * TILE_M;
    const int m0  = rg * 64 + l31;  // lane's first row (second = m0+32)

    // ---- stage: P[128][64] -> bf16 swizzled; X[128][32] -> Xl[m][i] ----
    {
        const float* Pb = Pg + (size_t)tile0 * PD;
#pragma unroll
        for (int s = 0; s < 8; ++s) {
            const int id = t + 256 * s;
            const int r = id >> 4, ch = id & 15;
            f32x4 v = *(const f32x4*)(Pb + (size_t)r * PD + ch * 4);
            bf16x4 bv;
#pragma unroll
            for (int j = 0; j < 4; ++j) bv[j] = (__bf16)v[j];
            char* dst = (char*)U.p + r * 128
                      + ((((ch >> 1) ^ (r & 7)) << 4) | ((ch & 1) * 8));
            *(bf16x4*)dst = bv;
        }
        const float* Xb = Xg + (size_t)tile0 * CI;
#pragma unroll
        for (int s = 0; s < 4; ++s) {
            const int id = t + 256 * s;
            const int r = id >> 3, ch = id & 7;
            f32x4 v = *(const f32x4*)(Xb + (size_t)r * CI + ch * 4);
#pragma unroll
            for (int j = 0; j < 4; ++j) Xl[r * XLS + ch * 4 + j] = v[j];
        }
    }
    __syncthreads();

    // ---- B fragments (P^T) for rows m0, m0+32 (m0&7 == l31&7) ----
    bf16x8 bfA[4], bfB[4];
#pragma unroll
    for (int kq = 0; kq < 4; ++kq) {
        const int g = ((kq * 2 + hi) ^ (l31 & 7)) << 4;
        bfA[kq] = *(const bf16x8*)((const char*)U.p + m0 * 128 + g);
        bfB[kq] = *(const bf16x8*)((const char*)U.p + (m0 + 32) * 128 + g);
    }

    // ---- i-loop over this wave's half: 16 steps, 2-deep A prefetch ----
    f32x16 oA = {}, oB = {};
    const __bf16* abase = wsF + (size_t)(ih * 16) * 2048
                        + (size_t)hi * 256 + (size_t)l31 * 8;
    const float* xb0 = &Xl[m0 * XLS + ih * 16];          // imm-offset reads
    const float* xb1 = &Xl[(m0 + 32) * XLS + ih * 16];

    bf16x8 a0[4], a1[4];
    auto aload = [&](int i, bf16x8* buf) {   // i local 0..15
        const __bf16* ap = abase + (size_t)i * 2048;
        buf[0] = *(const bf16x8*)(ap);
        buf[1] = *(const bf16x8*)(ap +  512);
        buf[2] = *(const bf16x8*)(ap + 1024);
        buf[3] = *(const bf16x8*)(ap + 1536);
    };
    auto step = [&](const bf16x8* a, int i) {
        const float xl = xb0[i];
        const float xh = xb1[i];
        f32x16 c0 = {}, c1 = {};
#pragma unroll
        for (int kq = 0; kq < 4; ++kq) {     // 2 independent chains
            c0 = __builtin_amdgcn_mfma_f32_32x32x16_bf16(a[kq], bfA[kq], c0, 0, 0, 0);
            c1 = __builtin_amdgcn_mfma_f32_32x32x16_bf16(a[kq], bfB[kq], c1, 0, 0, 0);
        }
#pragma unroll
        for (int r = 0; r < 16; ++r) {
            oA[r] += fmaxf(c0[r], 0.0f) * xl;
            oB[r] += fmaxf(c1[r], 0.0f) * xh;
        }
    };

    aload(0, a0);
    aload(1, a1);
    for (int ii = 0; ii < 8; ++ii) {
        step(a0, 2 * ii);
        if (ii < 7) aload(2 * ii + 2, a0);
        step(a1, 2 * ii + 1);
        if (ii < 7) aload(2 * ii + 3, a1);
    }

    // ---- combine partials: ih=1 publishes, ih=0 adds and stores ----
    __syncthreads();                       // bfrag reads long done; U.p -> U.o
    if (ih == 1) {
        const int ob = (rg * 64 + l) * OLS;
#pragma unroll
        for (int r = 0; r < 16; ++r) {
            U.o[ob + r]      = oA[r];
            U.o[ob + 16 + r] = oB[r];
        }
    }
    __syncthreads();
    if (ih == 0) {
        const int ob = (rg * 64 + l) * OLS;
#pragma unroll
        for (int r = 0; r < 16; ++r) {
            oA[r] += U.o[ob + r];
            oB[r] += U.o[ob + 16 + r];
        }
        // direct stores (R14-main pattern): lane rows m0/m0+32, cols 4*hi+8*rq
        float* orow  = outg + (size_t)(tile0 + m0) * CO + 4 * hi;
        float* orow2 = orow + 32 * CO;
#pragma unroll
        for (int rq = 0; rq < 4; ++rq) {
            f32x4 vA, vB;
#pragma unroll
            for (int j = 0; j < 4; ++j) { vA[j] = oA[4*rq + j]; vB[j] = oB[4*rq + j]; }
            *(f32x4*)(orow  + 8 * rq) = vA;
            *(f32x4*)(orow2 + 8 * rq) = vB;
        }
    }
}

extern "C" void kernel_launch(void* const* d_in, const int* in_sizes, int n_in,
                              void* d_out, int out_size, void* d_ws, size_t ws_size,
                              hipStream_t stream)
{
    const float* X  = (const float*)d_in[0];
    const float* P  = (const float*)d_in[1];
    const float* Wk = (const float*)d_in[2];
    float* out  = (float*)d_out;
    __bf16* wsF = (__bf16*)d_ws;   // 1024*64*2 = 128 KB

    wk_pack_kernel<<<dim3(QDIM / 32), dim3(256), 0, stream>>>(Wk, wsF);
    cond_dense_kernel<<<dim3(NBLK), dim3(WG_THREADS), 0, stream>>>(X, P, wsF, out);
}

// Round 17
// 36.680 us; speedup vs baseline: 6.1448x; 2.3831x over previous
//
#include <hip/hip_runtime.h>

#define CI 32
#define CO 32
#define PD 64
#define QDIM 1024
#define M_TOTAL (32*4096)
#define TILE_M 128                 // per WG: waves = (rg in 0..1) x (ih in 0..1)
#define NBLK (M_TOTAL/TILE_M)      // 1024 WGs; 4096 waves total = 16/CU supply
#define WG_THREADS 256
#define XLS 33                     // Xl[m][i]: reads (l31+i)%32 conflict-free
#define OLS 33                     // Ol[lane][r]: (l+r)%32, 2-way free

typedef float  f32x4  __attribute__((ext_vector_type(4)));
typedef float  f32x16 __attribute__((ext_vector_type(16)));
typedef __bf16 bf16x4 __attribute__((ext_vector_type(4)));
typedef __bf16 bf16x8 __attribute__((ext_vector_type(8)));

// ---- one-time: Wk [64][1024] f32 -> wsF, MFMA-A-fragment-linear layout ----
// wsF idx = (q>>5)*2048 + (k>>3)*256 + (q&31)*8 + (k&7); per i, frag f, lane
// (l31,hi) reads contiguous: wsF + i*2048 + (2f+hi)*256 + l31*8
__global__ __launch_bounds__(256)
void wk_pack_kernel(const float* __restrict__ Wk, __bf16* __restrict__ wsF)
{
    __shared__ float tile[64][33];
    const int q0 = blockIdx.x * 32;
    const int t  = threadIdx.x;
#pragma unroll
    for (int s = 0; s < 2; ++s) {
        const int idx = t + s * 256;
        const int k = idx >> 3, ch = idx & 7;
        f32x4 v = *(const f32x4*)(Wk + (size_t)k * QDIM + q0 + ch * 4);
        tile[k][ch*4+0] = v[0]; tile[k][ch*4+1] = v[1];
        tile[k][ch*4+2] = v[2]; tile[k][ch*4+3] = v[3];
    }
    __syncthreads();
    const int qq = t >> 3;
    const int g  = t & 7;
    bf16x8 o;
#pragma unroll
    for (int j = 0; j < 8; ++j) o[j] = (__bf16)tile[g*8 + j][qq];
    *(bf16x8*)(wsF + (size_t)blockIdx.x * 2048 + g * 256 + qq * 8) = o;
}

// i-SPLIT scheme at the R12-proven register allocation:
//   - R15 ablation: STEP body (MFMA->relu+fma VALU) is the wall; it needs
//     ~4 waves/SIMD of TLP to cover its dependency chains.
//   - R12: VGPR=104 binary (this live set, launch_bounds(256,2)) = 4 waves/
//     SIMD capable, but grid supplied only 2/SIMD.
//   - R16: supply fixed (4096 waves) but launch_bounds(256,4) forced VGPR=64
//     + spills (WRITE 134MB).
// This round: R16 structure + launch_bounds(256,2). ONE variable vs R16.
__global__ __launch_bounds__(WG_THREADS, 2)
void cond_dense_kernel(const float* __restrict__ Xg, const float* __restrict__ Pg,
                       const __bf16* __restrict__ wsF, float* __restrict__ outg)
{
    __shared__ union {
        __bf16 p[TILE_M * PD];       // 16384 B: P-tile (dead after bfrag)
        float  o[2 * 64 * OLS];      // 16896 B: partial-sum exchange
    } U;
    __shared__ float Xl[TILE_M * XLS];   // 16896 B: X row-major [m][i]

    const int t   = threadIdx.x;
    const int l   = t & 63;
    const int w   = t >> 6;
    const int rg  = w & 1;          // row-group: rows rg*64 .. rg*64+63
    const int ih  = w >> 1;         // i-half: i in ih*16 .. ih*16+15
    const int l31 = l & 31;
    const int hi  = l >> 5;
    const int tile0 = blockIdx.x * TILE_M;
    const int m0  = rg * 64 + l31;  // lane's first row (second = m0+32)

    // ---- stage: P[128][64] -> bf16 swizzled; X[128][32] -> Xl[m][i] ----
    {
        const float* Pb = Pg + (size_t)tile0 * PD;
#pragma unroll
        for (int s = 0; s < 8; ++s) {
            const int id = t + 256 * s;
            const int r = id >> 4, ch = id & 15;
            f32x4 v = *(const f32x4*)(Pb + (size_t)r * PD + ch * 4);
            bf16x4 bv;
#pragma unroll
            for (int j = 0; j < 4; ++j) bv[j] = (__bf16)v[j];
            char* dst = (char*)U.p + r * 128
                      + ((((ch >> 1) ^ (r & 7)) << 4) | ((ch & 1) * 8));
            *(bf16x4*)dst = bv;
        }
        const float* Xb = Xg + (size_t)tile0 * CI;
#pragma unroll
        for (int s = 0; s < 4; ++s) {
            const int id = t + 256 * s;
            const int r = id >> 3, ch = id & 7;
            f32x4 v = *(const f32x4*)(Xb + (size_t)r * CI + ch * 4);
#pragma unroll
            for (int j = 0; j < 4; ++j) Xl[r * XLS + ch * 4 + j] = v[j];
        }
    }
    __syncthreads();

    // ---- B fragments (P^T) for rows m0, m0+32 (m0&7 == l31&7) ----
    bf16x8 bfA[4], bfB[4];
#pragma unroll
    for (int kq = 0; kq < 4; ++kq) {
        const int g = ((kq * 2 + hi) ^ (l31 & 7)) << 4;
        bfA[kq] = *(const bf16x8*)((const char*)U.p + m0 * 128 + g);
        bfB[kq] = *(const bf16x8*)((const char*)U.p + (m0 + 32) * 128 + g);
    }

    // ---- i-loop over this wave's half: 16 steps, 2-deep A prefetch ----
    f32x16 oA = {}, oB = {};
    const __bf16* abase = wsF + (size_t)(ih * 16) * 2048
                        + (size_t)hi * 256 + (size_t)l31 * 8;
    const float* xb0 = &Xl[m0 * XLS + ih * 16];          // imm-offset reads
    const float* xb1 = &Xl[(m0 + 32) * XLS + ih * 16];

    bf16x8 a0[4], a1[4];
    auto aload = [&](int i, bf16x8* buf) {   // i local 0..15
        const __bf16* ap = abase + (size_t)i * 2048;
        buf[0] = *(const bf16x8*)(ap);
        buf[1] = *(const bf16x8*)(ap +  512);
        buf[2] = *(const bf16x8*)(ap + 1024);
        buf[3] = *(const bf16x8*)(ap + 1536);
    };
    auto step = [&](const bf16x8* a, int i) {
        const float xl = xb0[i];
        const float xh = xb1[i];
        f32x16 c0 = {}, c1 = {};
#pragma unroll
        for (int kq = 0; kq < 4; ++kq) {     // 2 independent chains
            c0 = __builtin_amdgcn_mfma_f32_32x32x16_bf16(a[kq], bfA[kq], c0, 0, 0, 0);
            c1 = __builtin_amdgcn_mfma_f32_32x32x16_bf16(a[kq], bfB[kq], c1, 0, 0, 0);
        }
#pragma unroll
        for (int r = 0; r < 16; ++r) {
            oA[r] += fmaxf(c0[r], 0.0f) * xl;
            oB[r] += fmaxf(c1[r], 0.0f) * xh;
        }
    };

    aload(0, a0);
    aload(1, a1);
    for (int ii = 0; ii < 8; ++ii) {
        step(a0, 2 * ii);
        if (ii < 7) aload(2 * ii + 2, a0);
        step(a1, 2 * ii + 1);
        if (ii < 7) aload(2 * ii + 3, a1);
    }

    // ---- combine partials: ih=1 publishes, ih=0 adds and stores ----
    __syncthreads();                       // bfrag reads long done; U.p -> U.o
    if (ih == 1) {
        const int ob = (rg * 64 + l) * OLS;
#pragma unroll
        for (int r = 0; r < 16; ++r) {
            U.o[ob + r]      = oA[r];
            U.o[ob + 16 + r] = oB[r];
        }
    }
    __syncthreads();
    if (ih == 0) {
        const int ob = (rg * 64 + l) * OLS;
#pragma unroll
        for (int r = 0; r < 16; ++r) {
            oA[r] += U.o[ob + r];
            oB[r] += U.o[ob + 16 + r];
        }
        // direct stores: lane rows m0/m0+32, cols 4*hi+8*rq
        float* orow  = outg + (size_t)(tile0 + m0) * CO + 4 * hi;
        float* orow2 = orow + 32 * CO;
#pragma unroll
        for (int rq = 0; rq < 4; ++rq) {
            f32x4 vA, vB;
#pragma unroll
            for (int j = 0; j < 4; ++j) { vA[j] = oA[4*rq + j]; vB[j] = oB[4*rq + j]; }
            *(f32x4*)(orow  + 8 * rq) = vA;
            *(f32x4*)(orow2 + 8 * rq) = vB;
        }
    }
}

extern "C" void kernel_launch(void* const* d_in, const int* in_sizes, int n_in,
                              void* d_out, int out_size, void* d_ws, size_t ws_size,
                              hipStream_t stream)
{
    const float* X  = (const float*)d_in[0];
    const float* P  = (const float*)d_in[1];
    const float* Wk = (const float*)d_in[2];
    float* out  = (float*)d_out;
    __bf16* wsF = (__bf16*)d_ws;   // 1024*64*2 = 128 KB

    wk_pack_kernel<<<dim3(QDIM / 32), dim3(256), 0, stream>>>(Wk, wsF);
    cond_dense_kernel<<<dim3(NBLK), dim3(WG_THREADS), 0, stream>>>(X, P, wsF, out);
}